// Round 23
// baseline (181.847 us; speedup 1.0000x reference)
//
#include <hip/hip_runtime.h>
#include <hip/hip_bf16.h>

#define T_SEQ 2048
#define CDIM  1024
#define NH    16
#define HD    64
#define BATCH 4
#define MROWS (BATCH * T_SEQ)   // 8192
#define QSCALE 0.18033688011112042f   // 0.125 * log2(e)
#define LOG2E  1.4426950408889634f

typedef __attribute__((ext_vector_type(8))) short bf16x8;
typedef __attribute__((ext_vector_type(4))) float f32x4;

__device__ __forceinline__ ushort f2bf(float f) {
    unsigned u = __float_as_uint(f);
    unsigned r = (u + 0x7fffu + ((u >> 16) & 1u)) >> 16;
    return (ushort)r;
}

// compiler cast path (single v_cvt — m240: don't hand-write cvt_pk)
__device__ __forceinline__ ushort f2bf_hw(float f) {
    __hip_bfloat16 h = __float2bfloat16(f);
    return *reinterpret_cast<ushort*>(&h);
}

// async global->LDS, 16B per lane; LDS dest = wave-uniform base + lane*16
__device__ __forceinline__ void gload_lds16(const void* g, void* l) {
    __builtin_amdgcn_global_load_lds(
        (const __attribute__((address_space(1))) unsigned int*)g,
        (__attribute__((address_space(3))) unsigned int*)l, 16, 0, 0);
}

// ---------------------------------------------------------------------------
// fp32 -> bf16 elementwise (x), vectorized 4-wide, grid-stride
// ---------------------------------------------------------------------------
__global__ __launch_bounds__(256)
void cvt_bf16(const float* __restrict__ in, ushort* __restrict__ out, int n4)
{
    const int stride = gridDim.x * blockDim.x;
    for (int i = blockIdx.x * blockDim.x + threadIdx.x; i < n4; i += stride) {
        float4 v = *(const float4*)&in[(size_t)i * 4];
        ushort4 o;
        o.x = f2bf(v.x); o.y = f2bf(v.y); o.z = f2bf(v.z); o.w = f2bf(v.w);
        *(ushort4*)&out[(size_t)i * 4] = o;
    }
}

// ---------------------------------------------------------------------------
// fp32 [R][C] -> bf16 [C][R] transpose+convert, 32x32 LDS tile
// ---------------------------------------------------------------------------
__global__ __launch_bounds__(256)
void transpose_cvt(const float* __restrict__ in, ushort* __restrict__ out,
                   int R, int C)
{
    __shared__ float t[32][33];
    const int c0 = blockIdx.x * 32, r0 = blockIdx.y * 32;
    const int tx = threadIdx.x & 31, ty = threadIdx.x >> 5;   // 8 rows/pass
    #pragma unroll
    for (int rr = 0; rr < 32; rr += 8)
        t[rr + ty][tx] = in[(size_t)(r0 + rr + ty) * C + c0 + tx];
    __syncthreads();
    #pragma unroll
    for (int rr = 0; rr < 32; rr += 8)
        out[(size_t)(c0 + rr + ty) * R + r0 + tx] = f2bf(t[tx][rr + ty]);
}

// ---------------------------------------------------------------------------
// bf16 MFMA GEMM, 128x128 tile, BK=64, 256 threads = 4 waves (2x2).
// Staging via global_load_lds width=16 (verified r12: 515->236 us total).
// No XCD swizzle (r17 measured -13 us on this shape). SCATTER=0: fp32 direct.
// SCATTER=1: coalesced LDS-staged stores q/k [B,H,T,64], vT [B,H,64,T] (r10).
// ---------------------------------------------------------------------------
template<int SCATTER>
__global__ __launch_bounds__(256)
void gemm_mfma(const ushort* __restrict__ A, const ushort* __restrict__ Bt,
               float* __restrict__ C0, ushort* __restrict__ Q0,
               ushort* __restrict__ K0, ushort* __restrict__ V0,
               int M, int N, int K)
{
    __shared__ __align__(16) char LDSb[32768];
    char* Asm = LDSb;            // 16 KB A-tile during K-loop
    char* Bsm = LDSb + 16384;    // 16 KB B-tile during K-loop

    const int tid  = threadIdx.x;
    const int wave = tid >> 6;
    const int lane = tid & 63;
    const int lr   = lane & 15;
    const int lg   = lane >> 4;
    const int wr   = wave >> 1;
    const int wc   = wave & 1;
    const int m0   = blockIdx.x * 128;
    const int n0   = blockIdx.y * 128;

    const int prow = lane >> 3;          // 0..7 (row within 8-row group)
    const int pcb  = (lane & 7) * 16;    // byte col 0..112

    const f32x4 zero4 = {0.f, 0.f, 0.f, 0.f};
    f32x4 acc[4][4];
    #pragma unroll
    for (int i = 0; i < 4; ++i)
        #pragma unroll
        for (int j = 0; j < 4; ++j) acc[i][j] = zero4;

    const char* Abase = (const char*)A;
    const char* Bbase = (const char*)Bt;

    for (int k0 = 0; k0 < K; k0 += 64) {
        __syncthreads();               // previous tile's frag reads done
        #pragma unroll
        for (int p = 0; p < 4; ++p) {
            const int row = wave * 32 + p * 8 + prow;       // 0..127
            const int soff = pcb ^ ((row & 7) << 4);        // swizzled src col
            gload_lds16(Abase + ((size_t)(m0 + row) * K + k0) * 2 + soff,
                        Asm + (wave * 32 + p * 8) * 128);
            gload_lds16(Bbase + ((size_t)(n0 + row) * K + k0) * 2 + soff,
                        Bsm + (wave * 32 + p * 8) * 128);
        }
        __syncthreads();               // vmcnt drained -> tile ready

        #pragma unroll
        for (int ks = 0; ks < 2; ++ks) {
            bf16x8 af[4], bf[4];
            #pragma unroll
            for (int mt = 0; mt < 4; ++mt) {
                const int row = wr * 64 + mt * 16 + lr;
                af[mt] = *(const bf16x8*)(Asm + row * 128 +
                         ((ks * 64 + lg * 16) ^ ((row & 7) << 4)));
            }
            #pragma unroll
            for (int nt = 0; nt < 4; ++nt) {
                const int row = wc * 64 + nt * 16 + lr;
                bf[nt] = *(const bf16x8*)(Bsm + row * 128 +
                         ((ks * 64 + lg * 16) ^ ((row & 7) << 4)));
            }
            #pragma unroll
            for (int mt = 0; mt < 4; ++mt)
                #pragma unroll
                for (int nt = 0; nt < 4; ++nt)
                    acc[mt][nt] = __builtin_amdgcn_mfma_f32_16x16x32_bf16(
                        af[mt], bf[nt], acc[mt][nt], 0, 0, 0);
        }
    }

    if (SCATTER == 0) {
        #pragma unroll
        for (int mt = 0; mt < 4; ++mt)
            #pragma unroll
            for (int r4 = 0; r4 < 4; ++r4) {
                const int m = m0 + wr * 64 + mt * 16 + lg * 4 + r4;
                float* cr = C0 + (size_t)m * N + n0 + wc * 64;
                #pragma unroll
                for (int nt = 0; nt < 4; ++nt)
                    cr[nt * 16 + lr] = acc[mt][nt][r4];
            }
    } else {
        const int which = n0 >> 10;            // 0=q 1=k 2=v
        const int nn  = n0 & (CDIM - 1);
        const int h0  = nn >> 6;               // tile covers heads h0, h0+1
        const int b   = m0 >> 11;
        const int t0t = m0 & (T_SEQ - 1);
        __syncthreads();                       // frag reads done; reuse LDS
        if (which < 2) {
            const float qs = (which == 0) ? QSCALE : 1.0f;
            #pragma unroll
            for (int mt = 0; mt < 4; ++mt)
                #pragma unroll
                for (int r4 = 0; r4 < 4; ++r4) {
                    const int row = wr * 64 + mt * 16 + lg * 4 + r4;
                    char* rp = LDSb + row * 256;
                    const int swr = (row & 7) << 4;
                    #pragma unroll
                    for (int nt = 0; nt < 4; ++nt) {
                        const int col = wc * 64 + nt * 16 + lr;
                        *(ushort*)(rp + ((col * 2) ^ swr)) =
                            f2bf(acc[mt][nt][r4] * qs);
                    }
                }
            __syncthreads();
            ushort* dstb = ((which == 0) ? Q0 : K0) + (size_t)(b * NH) * T_SEQ * HD;
            #pragma unroll
            for (int it = 0; it < 8; ++it) {
                const int cid  = it * 256 + tid;
                const int row  = cid >> 4;            // t_local
                const int colb = (cid & 15) * 16;     // byte col in 256B row
                int4 vdat = *(const int4*)(LDSb + row * 256 +
                                           (colb ^ ((row & 7) << 4)));
                const int col = colb >> 1;            // element col 0..127
                const int h   = h0 + (col >> 6);
                const int dc  = col & 63;
                *(int4*)&dstb[((size_t)h * T_SEQ + t0t + row) * HD + dc] = vdat;
            }
        } else {
            #pragma unroll
            for (int mt = 0; mt < 4; ++mt)
                #pragma unroll
                for (int r4 = 0; r4 < 4; ++r4) {
                    const int trow = wr * 64 + mt * 16 + lg * 4 + r4;  // t_local
                    #pragma unroll
                    for (int nt = 0; nt < 4; ++nt) {
                        const int col = wc * 64 + nt * 16 + lr;
                        *(ushort*)(LDSb + col * 256 +
                                   ((trow * 2) ^ ((col & 7) << 4))) =
                            f2bf(acc[mt][nt][r4]);
                    }
                }
            __syncthreads();
            ushort* vbase = V0 + (size_t)(b * NH) * HD * T_SEQ;
            #pragma unroll
            for (int it = 0; it < 8; ++it) {
                const int cid = it * 256 + tid;
                const int col = cid >> 4;             // h*64+d
                const int tb  = (cid & 15) * 16;      // byte offset in t-row
                int4 vdat = *(const int4*)(LDSb + col * 256 +
                                           (tb ^ ((col & 7) << 4)));
                const int h = h0 + (col >> 6);
                const int d = col & 63;
                *(int4*)&vbase[((size_t)h * HD + d) * T_SEQ + t0t + (tb >> 1)] = vdat;
            }
        }
    }
}

// ---------------------------------------------------------------------------
// Flash attention, bf16 MFMA, causal + rel-bias, fixed-max softmax.
// r23: DOUBLE-BUFFERED K/V LDS — one barrier per k-tile instead of two.
// Legality: end-of-iteration barrier (with its vmcnt/lgkmcnt drain) both
// publishes tile kt+1's ds_writes and retires all reads of buf[kt&1], which
// is the buffer written in iteration kt+1. Prologue: write buf0, barrier
// (also publishes rbs), prefetch tile 1. Barriers/pass: nkt+1 vs 2*nkt.
// LDS 40->56 KB: still 2 blocks/CU (grid 512 = 2/CU anyway).
// Base: r18/r22 verified (attn 83.7 us): KVBLK=64, reg-prefetch, pairing,
// fixed-max softmax, interior fast path, HW bf16 casts, MFMA row-sum.
// ---------------------------------------------------------------------------
__global__ __launch_bounds__(512, 4)
void attn_mfma(const ushort* __restrict__ qb, const ushort* __restrict__ kb,
               const ushort* __restrict__ vb, const float* __restrict__ rb,
               ushort* __restrict__ y)
{
    __shared__ __align__(16) char LDS[57344];
    char*  KsB = LDS;                      // 16 KB [2][64*128]
    char*  VtB = LDS + 16384;              // 16 KB [2][64*128]
    char*  PsB = LDS + 32768;              // 16 KB [8 waves][16*128]
    float* rbs = (float*)(LDS + 49152);    // 8 KB (scaled by log2e)

    const int tid  = threadIdx.x;
    const int wave = tid >> 6;
    const int lane = tid & 63;
    const int lr   = lane & 15;
    const int lg   = lane >> 4;
    const int bh   = blockIdx.x;
    const int h    = bh & (NH - 1);
    const int b    = bh >> 4;
    const int qtA  = 15 - (int)blockIdx.y;    // big tile first (8..15)
    const int qtB  = (int)blockIdx.y;         // small tile (0..7)

    for (int i = tid; i < qtA * 128 + 128; i += 512)
        rbs[i] = rb[(size_t)i * NH + h] * LOG2E;

    const char* kbp = (const char*)(kb + (size_t)bh * T_SEQ * HD);
    const char* vbp = (const char*)(vb + (size_t)bh * HD * T_SEQ);

    const int r_st  = tid >> 3;
    const int cb    = (tid & 7) * 16;
    const int sw_st = (r_st & 7) << 4;

    const f32x4 zero4 = {0.f, 0.f, 0.f, 0.f};
    const short onebf = (short)0x3F80;                // bf16 1.0
    const bf16x8 ones = {onebf, onebf, onebf, onebf, onebf, onebf, onebf, onebf};

    #pragma unroll 1
    for (int pass = 0; pass < 2; ++pass) {
        const int qt = pass ? qtB : qtA;
        const int q0 = qt * 128;
        const int nkt = 2 * (qt + 1);         // >= 2 always

        const ushort* qrow = qb + ((size_t)bh * T_SEQ + q0 + wave * 16 + lr) * HD;
        const bf16x8 aq0 = *(const bf16x8*)(qrow + lg * 8);
        const bf16x8 aq1 = *(const bf16x8*)(qrow + 32 + lg * 8);

        f32x4 Oa[4] = {zero4, zero4, zero4, zero4};
        f32x4 lacc = zero4;

        // prologue: stage tile 0 into buf0 (prior pass's reads of buf0 were
        // retired by its final iteration barrier; pass 0: no prior readers)
        int4 kreg = *(const int4*)(kbp + (size_t)r_st * HD * 2 + cb);
        int4 vreg = *(const int4*)(vbp + (size_t)r_st * T_SEQ * 2 + cb);
        *(int4*)(KsB + r_st * 128 + (cb ^ sw_st)) = kreg;
        *(int4*)(VtB + r_st * 128 + (cb ^ sw_st)) = vreg;
        __syncthreads();                      // buf0 (and rbs) visible
        kreg = *(const int4*)(kbp + (size_t)(64 + r_st) * HD * 2 + cb);
        vreg = *(const int4*)(vbp + ((size_t)r_st * T_SEQ + 64) * 2 + cb);

        for (int kt = 0; kt < nkt; ++kt) {
            const int j0 = kt * 64;
            const char* Kc = KsB + (kt & 1) * 8192;
            const char* Vc = VtB + (kt & 1) * 8192;

            if (kt + 1 < nkt) {               // write next tile into other buf
                char* Kn = KsB + ((kt + 1) & 1) * 8192;
                char* Vn = VtB + ((kt + 1) & 1) * 8192;
                *(int4*)(Kn + r_st * 128 + (cb ^ sw_st)) = kreg;
                *(int4*)(Vn + r_st * 128 + (cb ^ sw_st)) = vreg;
                if (kt + 2 < nkt) {           // prefetch tile kt+2
                    const int j2 = j0 + 128;
                    kreg = *(const int4*)(kbp + (size_t)(j2 + r_st) * HD * 2 + cb);
                    vreg = *(const int4*)(vbp + ((size_t)r_st * T_SEQ + j2) * 2 + cb);
                }
            }

            // S = Q K^T (q pre-scaled by 0.125*log2e; bias pre-scaled)
            f32x4 sa[4] = {zero4, zero4, zero4, zero4};
            #pragma unroll
            for (int nt = 0; nt < 4; ++nt) {
                const int row = nt * 16 + lr;
                const int sw  = (row & 7) << 4;
                bf16x8 bk0 = *(const bf16x8*)(Kc + row * 128 + ((lg * 16) ^ sw));
                bf16x8 bk1 = *(const bf16x8*)(Kc + row * 128 + ((64 + lg * 16) ^ sw));
                sa[nt] = __builtin_amdgcn_mfma_f32_16x16x32_bf16(aq0, bk0, sa[nt], 0, 0, 0);
                sa[nt] = __builtin_amdgcn_mfma_f32_16x16x32_bf16(aq1, bk1, sa[nt], 0, 0, 0);
            }

            // fixed-max softmax: p = causal ? exp2(s+bias) : 0  (m == 0)
            const bool interior = (j0 + 63) <= (q0 + wave * 16);  // wave-uniform
            if (interior) {
                #pragma unroll
                for (int r4 = 0; r4 < 4; ++r4) {
                    const int gi = q0 + wave * 16 + lg * 4 + r4;
                    const int prow = lg * 4 + r4;
                    char* pw = PsB + wave * 2048 + prow * 128;
                    const int swp = (prow & 7) << 4;
                    #pragma unroll
                    for (int nt = 0; nt < 4; ++nt) {
                        const int gj = j0 + nt * 16 + lr;
                        const float p = exp2f(sa[nt][r4] + rbs[gi - gj]);
                        *(ushort*)(pw + (((nt * 16 + lr) * 2) ^ swp)) = f2bf_hw(p);
                    }
                }
            } else {
                #pragma unroll
                for (int r4 = 0; r4 < 4; ++r4) {
                    const int gi = q0 + wave * 16 + lg * 4 + r4;
                    const int prow = lg * 4 + r4;
                    char* pw = PsB + wave * 2048 + prow * 128;
                    const int swp = (prow & 7) << 4;
                    #pragma unroll
                    for (int nt = 0; nt < 4; ++nt) {
                        const int gj = j0 + nt * 16 + lr;
                        const float p = (gj <= gi)
                            ? exp2f(sa[nt][r4] + rbs[gi - gj]) : 0.0f;
                        *(ushort*)(pw + (((nt * 16 + lr) * 2) ^ swp)) = f2bf_hw(p);
                    }
                }
            }
            // no barrier: PsB is wave-private (lgkmcnt orders), Kc/Vc stable

            bf16x8 ap0 = *(const bf16x8*)(PsB + wave * 2048 + lr * 128 + ((lg * 16) ^ ((lr & 7) << 4)));
            bf16x8 ap1 = *(const bf16x8*)(PsB + wave * 2048 + lr * 128 + ((64 + lg * 16) ^ ((lr & 7) << 4)));
            // row-sum of P on the MFMA pipe: every D column = rowsum
            lacc = __builtin_amdgcn_mfma_f32_16x16x32_bf16(ap0, ones, lacc, 0, 0, 0);
            lacc = __builtin_amdgcn_mfma_f32_16x16x32_bf16(ap1, ones, lacc, 0, 0, 0);
            #pragma unroll
            for (int dt = 0; dt < 4; ++dt) {
                const int row = dt * 16 + lr;
                const int sw  = (row & 7) << 4;
                bf16x8 bv0 = *(const bf16x8*)(Vc + row * 128 + ((lg * 16) ^ sw));
                bf16x8 bv1 = *(const bf16x8*)(Vc + row * 128 + ((64 + lg * 16) ^ sw));
                Oa[dt] = __builtin_amdgcn_mfma_f32_16x16x32_bf16(ap0, bv0, Oa[dt], 0, 0, 0);
                Oa[dt] = __builtin_amdgcn_mfma_f32_16x16x32_bf16(ap1, bv1, Oa[dt], 0, 0, 0);
            }

            __syncthreads();   // publishes buf[(kt+1)&1]; retires reads of buf[kt&1]
        }

        // l = lacc[r4] (row lg*4+r4, every column identical) — no butterfly
        #pragma unroll
        for (int r4 = 0; r4 < 4; ++r4) {
            const float inv = 1.0f / lacc[r4];
            const int t = q0 + wave * 16 + lg * 4 + r4;
            ushort* yr = y + ((size_t)(b * T_SEQ + t)) * CDIM + h * HD;
            #pragma unroll
            for (int dt = 0; dt < 4; ++dt) yr[dt * 16 + lr] = f2bf_hw(Oa[dt][r4] * inv);
        }
    }
}

extern "C" void kernel_launch(void* const* d_in, const int* in_sizes, int n_in,
                              void* d_out, int out_size, void* d_ws, size_t ws_size,
                              hipStream_t stream)
{
    const float* x     = (const float*)d_in[0];   // [B,T,C]
    const float* Wqkv  = (const float*)d_in[1];   // [C,3C]
    const float* Wproj = (const float*)d_in[2];   // [C,C]
    const float* rb    = (const float*)d_in[3];   // [MAX_LEN,NH]
    float* out = (float*)d_out;                   // [B,T,C] fp32

    const size_t per = (size_t)BATCH * NH * T_SEQ * HD;   // 8.39M elems
    ushort* xb  = (ushort*)d_ws;                          // bf16 [M][C]
    ushort* wqT = xb + per;                               // bf16 [3C][C]
    ushort* wpT = wqT + (size_t)3 * CDIM * CDIM;          // bf16 [C][C]
    ushort* qw  = wpT + (size_t)CDIM * CDIM;              // bf16 [B,H,T,64] (pre-scaled)
    ushort* kw  = qw + per;
    ushort* vw  = kw + per;                               // bf16 [B,H,64,T]
    ushort* yb  = vw + per;                               // bf16 [B,T,C]
    const size_t need = (per * 5 + (size_t)4 * CDIM * CDIM) * sizeof(ushort);
    if (ws_size < need) return;

    cvt_bf16<<<2048, 256, 0, stream>>>(x, xb, (int)(per / 4));
    transpose_cvt<<<dim3(3 * CDIM / 32, CDIM / 32), 256, 0, stream>>>(Wqkv, wqT, CDIM, 3 * CDIM);
    transpose_cvt<<<dim3(CDIM / 32, CDIM / 32), 256, 0, stream>>>(Wproj, wpT, CDIM, CDIM);

    dim3 g1(MROWS / 128, (3 * CDIM) / 128);               // 64 x 24
    gemm_mfma<1><<<g1, dim3(256), 0, stream>>>(xb, wqT, nullptr, qw, kw, vw,
                                               MROWS, 3 * CDIM, CDIM);

    dim3 g2(BATCH * NH, 8);                               // paired q-tiles: uniform 34 k-tiles/block
    attn_mfma<<<g2, dim3(512), 0, stream>>>(qw, kw, vw, rb, yb);

    dim3 g3(MROWS / 128, CDIM / 128);                     // 64 x 8
    gemm_mfma<0><<<g3, dim3(256), 0, stream>>>(yb, wpT, out, nullptr, nullptr, nullptr,
                                               MROWS, CDIM, CDIM);
}

// Round 24
// 180.225 us; speedup vs baseline: 1.0090x; 1.0090x over previous
//
#include <hip/hip_runtime.h>
#include <hip/hip_bf16.h>

#define T_SEQ 2048
#define CDIM  1024
#define NH    16
#define HD    64
#define BATCH 4
#define MROWS (BATCH * T_SEQ)   // 8192
#define QSCALE 0.18033688011112042f   // 0.125 * log2(e)
#define LOG2E  1.4426950408889634f

typedef __attribute__((ext_vector_type(8))) short bf16x8;
typedef __attribute__((ext_vector_type(4))) float f32x4;

__device__ __forceinline__ ushort f2bf(float f) {
    unsigned u = __float_as_uint(f);
    unsigned r = (u + 0x7fffu + ((u >> 16) & 1u)) >> 16;
    return (ushort)r;
}

// compiler cast path (single v_cvt — m240: don't hand-write cvt_pk)
__device__ __forceinline__ ushort f2bf_hw(float f) {
    __hip_bfloat16 h = __float2bfloat16(f);
    return *reinterpret_cast<ushort*>(&h);
}

// async global->LDS, 16B per lane; LDS dest = wave-uniform base + lane*16
__device__ __forceinline__ void gload_lds16(const void* g, void* l) {
    __builtin_amdgcn_global_load_lds(
        (const __attribute__((address_space(1))) unsigned int*)g,
        (__attribute__((address_space(3))) unsigned int*)l, 16, 0, 0);
}

// ---------------------------------------------------------------------------
// fp32 -> bf16 elementwise (x), vectorized 4-wide, grid-stride
// ---------------------------------------------------------------------------
__global__ __launch_bounds__(256)
void cvt_bf16(const float* __restrict__ in, ushort* __restrict__ out, int n4)
{
    const int stride = gridDim.x * blockDim.x;
    for (int i = blockIdx.x * blockDim.x + threadIdx.x; i < n4; i += stride) {
        float4 v = *(const float4*)&in[(size_t)i * 4];
        ushort4 o;
        o.x = f2bf(v.x); o.y = f2bf(v.y); o.z = f2bf(v.z); o.w = f2bf(v.w);
        *(ushort4*)&out[(size_t)i * 4] = o;
    }
}

// ---------------------------------------------------------------------------
// fp32 [R][C] -> bf16 [C][R] transpose+convert, 32x32 LDS tile
// ---------------------------------------------------------------------------
__global__ __launch_bounds__(256)
void transpose_cvt(const float* __restrict__ in, ushort* __restrict__ out,
                   int R, int C)
{
    __shared__ float t[32][33];
    const int c0 = blockIdx.x * 32, r0 = blockIdx.y * 32;
    const int tx = threadIdx.x & 31, ty = threadIdx.x >> 5;   // 8 rows/pass
    #pragma unroll
    for (int rr = 0; rr < 32; rr += 8)
        t[rr + ty][tx] = in[(size_t)(r0 + rr + ty) * C + c0 + tx];
    __syncthreads();
    #pragma unroll
    for (int rr = 0; rr < 32; rr += 8)
        out[(size_t)(c0 + rr + ty) * R + r0 + tx] = f2bf(t[tx][rr + ty]);
}

// ---------------------------------------------------------------------------
// bf16 MFMA GEMM, 128x128 tile, BK=64, 256 threads = 4 waves (2x2).
// Staging via global_load_lds width=16 (verified r12: 515->236 us total).
// No XCD swizzle (r17 measured -13 us on this shape). SCATTER=0: fp32 direct.
// SCATTER=1: coalesced LDS-staged stores q/k [B,H,T,64], vT [B,H,64,T] (r10).
// QKV runs at ~920 TF — at the m97-structure ceiling (~900 TF documented).
// ---------------------------------------------------------------------------
template<int SCATTER>
__global__ __launch_bounds__(256)
void gemm_mfma(const ushort* __restrict__ A, const ushort* __restrict__ Bt,
               float* __restrict__ C0, ushort* __restrict__ Q0,
               ushort* __restrict__ K0, ushort* __restrict__ V0,
               int M, int N, int K)
{
    __shared__ __align__(16) char LDSb[32768];
    char* Asm = LDSb;            // 16 KB A-tile during K-loop
    char* Bsm = LDSb + 16384;    // 16 KB B-tile during K-loop

    const int tid  = threadIdx.x;
    const int wave = tid >> 6;
    const int lane = tid & 63;
    const int lr   = lane & 15;
    const int lg   = lane >> 4;
    const int wr   = wave >> 1;
    const int wc   = wave & 1;
    const int m0   = blockIdx.x * 128;
    const int n0   = blockIdx.y * 128;

    const int prow = lane >> 3;          // 0..7 (row within 8-row group)
    const int pcb  = (lane & 7) * 16;    // byte col 0..112

    const f32x4 zero4 = {0.f, 0.f, 0.f, 0.f};
    f32x4 acc[4][4];
    #pragma unroll
    for (int i = 0; i < 4; ++i)
        #pragma unroll
        for (int j = 0; j < 4; ++j) acc[i][j] = zero4;

    const char* Abase = (const char*)A;
    const char* Bbase = (const char*)Bt;

    for (int k0 = 0; k0 < K; k0 += 64) {
        __syncthreads();               // previous tile's frag reads done
        #pragma unroll
        for (int p = 0; p < 4; ++p) {
            const int row = wave * 32 + p * 8 + prow;       // 0..127
            const int soff = pcb ^ ((row & 7) << 4);        // swizzled src col
            gload_lds16(Abase + ((size_t)(m0 + row) * K + k0) * 2 + soff,
                        Asm + (wave * 32 + p * 8) * 128);
            gload_lds16(Bbase + ((size_t)(n0 + row) * K + k0) * 2 + soff,
                        Bsm + (wave * 32 + p * 8) * 128);
        }
        __syncthreads();               // vmcnt drained -> tile ready

        #pragma unroll
        for (int ks = 0; ks < 2; ++ks) {
            bf16x8 af[4], bf[4];
            #pragma unroll
            for (int mt = 0; mt < 4; ++mt) {
                const int row = wr * 64 + mt * 16 + lr;
                af[mt] = *(const bf16x8*)(Asm + row * 128 +
                         ((ks * 64 + lg * 16) ^ ((row & 7) << 4)));
            }
            #pragma unroll
            for (int nt = 0; nt < 4; ++nt) {
                const int row = wc * 64 + nt * 16 + lr;
                bf[nt] = *(const bf16x8*)(Bsm + row * 128 +
                         ((ks * 64 + lg * 16) ^ ((row & 7) << 4)));
            }
            #pragma unroll
            for (int mt = 0; mt < 4; ++mt)
                #pragma unroll
                for (int nt = 0; nt < 4; ++nt)
                    acc[mt][nt] = __builtin_amdgcn_mfma_f32_16x16x32_bf16(
                        af[mt], bf[nt], acc[mt][nt], 0, 0, 0);
        }
    }

    if (SCATTER == 0) {
        #pragma unroll
        for (int mt = 0; mt < 4; ++mt)
            #pragma unroll
            for (int r4 = 0; r4 < 4; ++r4) {
                const int m = m0 + wr * 64 + mt * 16 + lg * 4 + r4;
                float* cr = C0 + (size_t)m * N + n0 + wc * 64;
                #pragma unroll
                for (int nt = 0; nt < 4; ++nt)
                    cr[nt * 16 + lr] = acc[mt][nt][r4];
            }
    } else {
        const int which = n0 >> 10;            // 0=q 1=k 2=v
        const int nn  = n0 & (CDIM - 1);
        const int h0  = nn >> 6;               // tile covers heads h0, h0+1
        const int b   = m0 >> 11;
        const int t0t = m0 & (T_SEQ - 1);
        __syncthreads();                       // frag reads done; reuse LDS
        if (which < 2) {
            const float qs = (which == 0) ? QSCALE : 1.0f;
            #pragma unroll
            for (int mt = 0; mt < 4; ++mt)
                #pragma unroll
                for (int r4 = 0; r4 < 4; ++r4) {
                    const int row = wr * 64 + mt * 16 + lg * 4 + r4;
                    char* rp = LDSb + row * 256;
                    const int swr = (row & 7) << 4;
                    #pragma unroll
                    for (int nt = 0; nt < 4; ++nt) {
                        const int col = wc * 64 + nt * 16 + lr;
                        *(ushort*)(rp + ((col * 2) ^ swr)) =
                            f2bf(acc[mt][nt][r4] * qs);
                    }
                }
            __syncthreads();
            ushort* dstb = ((which == 0) ? Q0 : K0) + (size_t)(b * NH) * T_SEQ * HD;
            #pragma unroll
            for (int it = 0; it < 8; ++it) {
                const int cid  = it * 256 + tid;
                const int row  = cid >> 4;            // t_local
                const int colb = (cid & 15) * 16;     // byte col in 256B row
                int4 vdat = *(const int4*)(LDSb + row * 256 +
                                           (colb ^ ((row & 7) << 4)));
                const int col = colb >> 1;            // element col 0..127
                const int h   = h0 + (col >> 6);
                const int dc  = col & 63;
                *(int4*)&dstb[((size_t)h * T_SEQ + t0t + row) * HD + dc] = vdat;
            }
        } else {
            #pragma unroll
            for (int mt = 0; mt < 4; ++mt)
                #pragma unroll
                for (int r4 = 0; r4 < 4; ++r4) {
                    const int trow = wr * 64 + mt * 16 + lg * 4 + r4;  // t_local
                    #pragma unroll
                    for (int nt = 0; nt < 4; ++nt) {
                        const int col = wc * 64 + nt * 16 + lr;
                        *(ushort*)(LDSb + col * 256 +
                                   ((trow * 2) ^ ((col & 7) << 4))) =
                            f2bf(acc[mt][nt][r4]);
                    }
                }
            __syncthreads();
            ushort* vbase = V0 + (size_t)(b * NH) * HD * T_SEQ;
            #pragma unroll
            for (int it = 0; it < 8; ++it) {
                const int cid = it * 256 + tid;
                const int col = cid >> 4;             // h*64+d
                const int tb  = (cid & 15) * 16;      // byte offset in t-row
                int4 vdat = *(const int4*)(LDSb + col * 256 +
                                           (tb ^ ((col & 7) << 4)));
                const int h = h0 + (col >> 6);
                const int d = col & 63;
                *(int4*)&vbase[((size_t)h * HD + d) * T_SEQ + t0t + (tb >> 1)] = vdat;
            }
        }
    }
}

// ---------------------------------------------------------------------------
// Flash attention, bf16 MFMA, causal + rel-bias, fixed-max softmax.
// FINAL (r22): best measured — attn 84.0 us, total 180.4, absmax 0.015625.
// r23's double-buffer was neutral (83.3, within noise) — single-buffer kept
// for simplicity; reproduces m99/m100: explicit dbuf adds nothing once
// multi-wave co-residency hides the barrier drain.
// Structure: KVBLK=64, 40KB LDS, reg-prefetch (T14), pairing (r13, uniform
// 34 k-tiles/block), fixed-max softmax (r15: |s|<=~12 so m=0 is safe),
// interior fast path + HW bf16 casts + MFMA row-sum with B=ones (r18).
// ---------------------------------------------------------------------------
__global__ __launch_bounds__(512, 4)
void attn_mfma(const ushort* __restrict__ qb, const ushort* __restrict__ kb,
               const ushort* __restrict__ vb, const float* __restrict__ rb,
               ushort* __restrict__ y)
{
    __shared__ __align__(16) char KsB[64 * 128];      // 8 KB
    __shared__ __align__(16) char VtB[64 * 128];      // 8 KB
    __shared__ __align__(16) char PsB[8][16 * 128];   // 16 KB
    __shared__ float rbs[T_SEQ];                      // 8 KB (scaled by log2e)

    const int tid  = threadIdx.x;
    const int wave = tid >> 6;
    const int lane = tid & 63;
    const int lr   = lane & 15;
    const int lg   = lane >> 4;
    const int bh   = blockIdx.x;
    const int h    = bh & (NH - 1);
    const int b    = bh >> 4;
    const int qtA  = 15 - (int)blockIdx.y;    // big tile first (8..15)
    const int qtB  = (int)blockIdx.y;         // small tile (0..7)

    for (int i = tid; i < qtA * 128 + 128; i += 512)
        rbs[i] = rb[(size_t)i * NH + h] * LOG2E;

    const char* kbp = (const char*)(kb + (size_t)bh * T_SEQ * HD);
    const char* vbp = (const char*)(vb + (size_t)bh * HD * T_SEQ);

    const int r_st  = tid >> 3;
    const int cb    = (tid & 7) * 16;
    const int sw_st = (r_st & 7) << 4;

    const f32x4 zero4 = {0.f, 0.f, 0.f, 0.f};
    const short onebf = (short)0x3F80;                // bf16 1.0
    const bf16x8 ones = {onebf, onebf, onebf, onebf, onebf, onebf, onebf, onebf};

    #pragma unroll 1
    for (int pass = 0; pass < 2; ++pass) {
        const int qt = pass ? qtB : qtA;
        const int q0 = qt * 128;
        const int nkt = 2 * (qt + 1);

        const ushort* qrow = qb + ((size_t)bh * T_SEQ + q0 + wave * 16 + lr) * HD;
        const bf16x8 aq0 = *(const bf16x8*)(qrow + lg * 8);
        const bf16x8 aq1 = *(const bf16x8*)(qrow + 32 + lg * 8);

        f32x4 Oa[4] = {zero4, zero4, zero4, zero4};
        f32x4 lacc = zero4;

        int4 kreg = *(const int4*)(kbp + (size_t)r_st * HD * 2 + cb);
        int4 vreg = *(const int4*)(vbp + (size_t)r_st * T_SEQ * 2 + cb);

        for (int kt = 0; kt < nkt; ++kt) {
            const int j0 = kt * 64;
            __syncthreads();              // all waves done reading prev tile
            *(int4*)(KsB + r_st * 128 + (cb ^ sw_st)) = kreg;
            *(int4*)(VtB + r_st * 128 + (cb ^ sw_st)) = vreg;
            __syncthreads();              // tile ready
            if (kt + 1 < nkt) {           // prefetch next tile (hides HBM lat)
                const int j1 = j0 + 64;
                kreg = *(const int4*)(kbp + (size_t)(j1 + r_st) * HD * 2 + cb);
                vreg = *(const int4*)(vbp + ((size_t)r_st * T_SEQ + j1) * 2 + cb);
            }

            // S = Q K^T (q pre-scaled by 0.125*log2e; bias pre-scaled)
            f32x4 sa[4] = {zero4, zero4, zero4, zero4};
            #pragma unroll
            for (int nt = 0; nt < 4; ++nt) {
                const int row = nt * 16 + lr;
                const int sw  = (row & 7) << 4;
                bf16x8 bk0 = *(const bf16x8*)(KsB + row * 128 + ((lg * 16) ^ sw));
                bf16x8 bk1 = *(const bf16x8*)(KsB + row * 128 + ((64 + lg * 16) ^ sw));
                sa[nt] = __builtin_amdgcn_mfma_f32_16x16x32_bf16(aq0, bk0, sa[nt], 0, 0, 0);
                sa[nt] = __builtin_amdgcn_mfma_f32_16x16x32_bf16(aq1, bk1, sa[nt], 0, 0, 0);
            }

            // fixed-max softmax: p = causal ? exp2(s+bias) : 0  (m == 0)
            const bool interior = (j0 + 63) <= (q0 + wave * 16);  // wave-uniform
            if (interior) {
                #pragma unroll
                for (int r4 = 0; r4 < 4; ++r4) {
                    const int gi = q0 + wave * 16 + lg * 4 + r4;
                    const int prow = lg * 4 + r4;
                    char* pw = PsB[wave] + prow * 128;
                    const int swp = (prow & 7) << 4;
                    #pragma unroll
                    for (int nt = 0; nt < 4; ++nt) {
                        const int gj = j0 + nt * 16 + lr;
                        const float p = exp2f(sa[nt][r4] + rbs[gi - gj]);
                        *(ushort*)(pw + (((nt * 16 + lr) * 2) ^ swp)) = f2bf_hw(p);
                    }
                }
            } else {
                #pragma unroll
                for (int r4 = 0; r4 < 4; ++r4) {
                    const int gi = q0 + wave * 16 + lg * 4 + r4;
                    const int prow = lg * 4 + r4;
                    char* pw = PsB[wave] + prow * 128;
                    const int swp = (prow & 7) << 4;
                    #pragma unroll
                    for (int nt = 0; nt < 4; ++nt) {
                        const int gj = j0 + nt * 16 + lr;
                        const float p = (gj <= gi)
                            ? exp2f(sa[nt][r4] + rbs[gi - gj]) : 0.0f;
                        *(ushort*)(pw + (((nt * 16 + lr) * 2) ^ swp)) = f2bf_hw(p);
                    }
                }
            }
            // no barrier: PsB is wave-private (lgkmcnt orders), VtB stable

            bf16x8 ap0 = *(const bf16x8*)(PsB[wave] + lr * 128 + ((lg * 16) ^ ((lr & 7) << 4)));
            bf16x8 ap1 = *(const bf16x8*)(PsB[wave] + lr * 128 + ((64 + lg * 16) ^ ((lr & 7) << 4)));
            // row-sum of P on the MFMA pipe: every D column = rowsum
            lacc = __builtin_amdgcn_mfma_f32_16x16x32_bf16(ap0, ones, lacc, 0, 0, 0);
            lacc = __builtin_amdgcn_mfma_f32_16x16x32_bf16(ap1, ones, lacc, 0, 0, 0);
            #pragma unroll
            for (int dt = 0; dt < 4; ++dt) {
                const int row = dt * 16 + lr;
                const int sw  = (row & 7) << 4;
                bf16x8 bv0 = *(const bf16x8*)(VtB + row * 128 + ((lg * 16) ^ sw));
                bf16x8 bv1 = *(const bf16x8*)(VtB + row * 128 + ((64 + lg * 16) ^ sw));
                Oa[dt] = __builtin_amdgcn_mfma_f32_16x16x32_bf16(ap0, bv0, Oa[dt], 0, 0, 0);
                Oa[dt] = __builtin_amdgcn_mfma_f32_16x16x32_bf16(ap1, bv1, Oa[dt], 0, 0, 0);
            }
        }

        // l = lacc[r4] (row lg*4+r4, every column identical) — no butterfly
        #pragma unroll
        for (int r4 = 0; r4 < 4; ++r4) {
            const float inv = 1.0f / lacc[r4];
            const int t = q0 + wave * 16 + lg * 4 + r4;
            ushort* yr = y + ((size_t)(b * T_SEQ + t)) * CDIM + h * HD;
            #pragma unroll
            for (int dt = 0; dt < 4; ++dt) yr[dt * 16 + lr] = f2bf_hw(Oa[dt][r4] * inv);
        }
        __syncthreads();   // pass 0's K/V reads fully done before pass 1 restages
    }
}

extern "C" void kernel_launch(void* const* d_in, const int* in_sizes, int n_in,
                              void* d_out, int out_size, void* d_ws, size_t ws_size,
                              hipStream_t stream)
{
    const float* x     = (const float*)d_in[0];   // [B,T,C]
    const float* Wqkv  = (const float*)d_in[1];   // [C,3C]
    const float* Wproj = (const float*)d_in[2];   // [C,C]
    const float* rb    = (const float*)d_in[3];   // [MAX_LEN,NH]
    float* out = (float*)d_out;                   // [B,T,C] fp32

    const size_t per = (size_t)BATCH * NH * T_SEQ * HD;   // 8.39M elems
    ushort* xb  = (ushort*)d_ws;                          // bf16 [M][C]
    ushort* wqT = xb + per;                               // bf16 [3C][C]
    ushort* wpT = wqT + (size_t)3 * CDIM * CDIM;          // bf16 [C][C]
    ushort* qw  = wpT + (size_t)CDIM * CDIM;              // bf16 [B,H,T,64] (pre-scaled)
    ushort* kw  = qw + per;
    ushort* vw  = kw + per;                               // bf16 [B,H,64,T]
    ushort* yb  = vw + per;                               // bf16 [B,T,C]
    const size_t need = (per * 5 + (size_t)4 * CDIM * CDIM) * sizeof(ushort);
    if (ws_size < need) return;

    cvt_bf16<<<2048, 256, 0, stream>>>(x, xb, (int)(per / 4));
    transpose_cvt<<<dim3(3 * CDIM / 32, CDIM / 32), 256, 0, stream>>>(Wqkv, wqT, CDIM, 3 * CDIM);
    transpose_cvt<<<dim3(CDIM / 32, CDIM / 32), 256, 0, stream>>>(Wproj, wpT, CDIM, CDIM);

    dim3 g1(MROWS / 128, (3 * CDIM) / 128);               // 64 x 24
    gemm_mfma<1><<<g1, dim3(256), 0, stream>>>(xb, wqT, nullptr, qw, kw, vw,
                                               MROWS, 3 * CDIM, CDIM);

    dim3 g2(BATCH * NH, 8);                               // paired q-tiles: uniform 34 k-tiles/block
    attn_mfma<<<g2, dim3(512), 0, stream>>>(qw, kw, vw, rb, yb);

    dim3 g3(MROWS / 128, CDIM / 128);                     // 64 x 8
    gemm_mfma<0><<<g3, dim3(256), 0, stream>>>(yb, wpT, out, nullptr, nullptr, nullptr,
                                               MROWS, CDIM, CDIM);
}